// Round 7
// baseline (91.429 us; speedup 1.0000x reference)
//
#include <hip/hip_runtime.h>
#include <math.h>

// ---------------------------------------------------------------------------
// RopeAttentionModel reduced form:
//   x[s,:] = c_s * ones(HID)  =>  q/k/v rank-1: c_s * colsum(W)
//   scores[s,hg,k] = c_s*c_k * D[hg, s-k] / sqrt(128)
//   D[hg,d] = sum_j P[hg,j]*cos(d*f_j) - Q[hg,j]*sin(d*f_j)   (f64)
//   alpha[s,hg] = softmax-weighted mean of c_k  (scalar per (s,head))
//   out = A[S,32] @ M[32,4096],  M[hg,:] = Sv[h] . Wo[hg*128:+128, :]
// Streaming kernels: 16-row chunks, 16 loads issued up-front (one latency
// exposure per chunk), big grids for occupancy. alpha: lane-per-row scan.
// ---------------------------------------------------------------------------

#define HID 4096
#define NQH 32
#define NKVH 8
#define HD 128
#define CHQ 256                   // colsum chunks (16 rows each)
#define TS 64                     // s-rows per alpha block (one per lane)
#define RSQRT_HD 0.08838834764831845f
#define LOG2E    1.4426950408889634f

// partial column sum over 16 rows: all 16 float4 loads in flight at once
__device__ __forceinline__ void colsum_part16(const float* __restrict__ W,
                                              float* __restrict__ P,
                                              int cols4, int c4, int chunk) {
    const float4* b = reinterpret_cast<const float4*>(W);
    float4 tt[16];
    size_t p = (size_t)(chunk * 16) * cols4 + c4;
#pragma unroll
    for (int i = 0; i < 16; ++i) tt[i] = b[p + (size_t)i * cols4];
    float ax = 0.f, ay = 0.f, az = 0.f, aw = 0.f;
#pragma unroll
    for (int i = 0; i < 16; i += 4) {
        ax += (tt[i].x + tt[i+1].x) + (tt[i+2].x + tt[i+3].x);
        ay += (tt[i].y + tt[i+1].y) + (tt[i+2].y + tt[i+3].y);
        az += (tt[i].z + tt[i+1].z) + (tt[i+2].z + tt[i+3].z);
        aw += (tt[i].w + tt[i+1].w) + (tt[i+2].w + tt[i+3].w);
    }
    reinterpret_cast<float4*>(P)[(size_t)chunk * cols4 + c4] =
        make_float4(ax, ay, az, aw);
}

// ---- fused: Wq/Wk/Wv partial colsums + trig table + cp ----
__global__ __launch_bounds__(256, 4) void k_part(
        const int* __restrict__ ids,
        const float* __restrict__ Wq, const float* __restrict__ Wk,
        const float* __restrict__ Wv,
        float* __restrict__ Pq, float* __restrict__ Pk, float* __restrict__ Pv,
        float* __restrict__ cp, double* __restrict__ Tc,
        double* __restrict__ Ts, int S) {
    int t = blockIdx.x;
    int tid = threadIdx.x;
    int nxb = S >> 8;
    if (t < 4 * CHQ) {
        colsum_part16(Wq, Pq, NQH * HD / 4, (t & 3) * 256 + tid, t >> 2);
    } else if (t < 5 * CHQ) {
        colsum_part16(Wk, Pk, NKVH * HD / 4, tid, t - 4 * CHQ);
    } else if (t < 6 * CHQ) {
        colsum_part16(Wv, Pv, NKVH * HD / 4, tid, t - 5 * CHQ);
    } else {
        int u = t - 6 * CHQ;
        int j = u / nxb, xb = u - j * nxb;
        int dlt = xb * 256 + tid;
        double f = (double)(float)(1.0 / pow(10000.0, (double)j / 64.0));
        double sv, cv;
        sincos((double)dlt * f, &sv, &cv);
        Tc[(size_t)j * S + dlt] = cv;
        Ts[(size_t)j * S + dlt] = sv;
        if (j == 0) cp[dlt] = (float)ids[dlt];
    }
}

// ---- reduce partials -> Sq, Sk, Sv (6 blocks, 16-deep batches) ----
__global__ __launch_bounds__(256) void k_red(
        const float* __restrict__ Pq, const float* __restrict__ Pk,
        const float* __restrict__ Pv, float* __restrict__ Sq,
        float* __restrict__ Sk, float* __restrict__ Sv) {
    int t = blockIdx.x;
    const float* P; float* Sd; int cols4, c4;
    if (t < 4)      { P = Pq; Sd = Sq; cols4 = NQH * HD / 4; c4 = t * 256 + threadIdx.x; }
    else if (t == 4){ P = Pk; Sd = Sk; cols4 = NKVH * HD / 4; c4 = threadIdx.x; }
    else            { P = Pv; Sd = Sv; cols4 = NKVH * HD / 4; c4 = threadIdx.x; }
    const float4* b = reinterpret_cast<const float4*>(P);
    float ax = 0.f, ay = 0.f, az = 0.f, aw = 0.f;
    for (int c = 0; c < CHQ; c += 16) {
        float4 tt[16];
#pragma unroll
        for (int i = 0; i < 16; ++i) tt[i] = b[(size_t)(c + i) * cols4 + c4];
#pragma unroll
        for (int i = 0; i < 16; i += 4) {
            ax += (tt[i].x + tt[i+1].x) + (tt[i+2].x + tt[i+3].x);
            ay += (tt[i].y + tt[i+1].y) + (tt[i+2].y + tt[i+3].y);
            az += (tt[i].z + tt[i+1].z) + (tt[i+2].z + tt[i+3].z);
            aw += (tt[i].w + tt[i+1].w) + (tt[i+2].w + tt[i+3].w);
        }
    }
    reinterpret_cast<float4*>(Sd)[c4] = make_float4(ax, ay, az, aw);
}

// ---- fused: M slabs (Sv.Wo, 16 rows, loads up-front) + D table (f64) ----
__global__ __launch_bounds__(256, 4) void k_mid(
        const float* __restrict__ Sq, const float* __restrict__ Sk,
        const float* __restrict__ Sv, const float* __restrict__ Wo,
        const double* __restrict__ Tc, const double* __restrict__ Ts,
        float* __restrict__ Mp, float* __restrict__ D, int S) {
    int t = blockIdx.x;
    int tid = threadIdx.x;
    if (t < 1024) {
        // Mp[sl][hg][:] = Sv[h, sl*16:+16] . Wo[hg*128+sl*16 : +16, :]
        int sl = t & 7, x = (t >> 3) & 3, hg = t >> 5;
        int h = hg >> 2, dbase = hg * HD + sl * 16;
        int i4 = x * 256 + tid;
        const float4* b = reinterpret_cast<const float4*>(Wo);
        const float* sv = Sv + h * HD + sl * 16;
        float4 tt[16];
        size_t p = (size_t)dbase * (HID / 4) + i4;
#pragma unroll
        for (int i = 0; i < 16; ++i) tt[i] = b[p + (size_t)i * (HID / 4)];
        float ax = 0.f, ay = 0.f, az = 0.f, aw = 0.f;
#pragma unroll
        for (int i = 0; i < 16; ++i) {
            float ss = sv[i];
            ax += ss * tt[i].x; ay += ss * tt[i].y;
            az += ss * tt[i].z; aw += ss * tt[i].w;
        }
        reinterpret_cast<float4*>(Mp)[((size_t)sl * NQH + hg) * (HID / 4) + i4] =
            make_float4(ax, ay, az, aw);
    } else {
        // D[hg, dlt] = sum_j p[j]*cos - q[j]*sin   (f64)
        __shared__ double p[64], q[64];
        int u = t - 1024;
        int nxb = S >> 8;
        int hg = u / nxb, xb = u - hg * nxb, h = hg >> 2;
        if (tid < 64) {
            double a1 = Sq[hg * HD + tid], a2 = Sq[hg * HD + tid + 64];
            double b1 = Sk[h * HD + tid],  b2 = Sk[h * HD + tid + 64];
            p[tid] = a1 * b1 + a2 * b2;
            q[tid] = a2 * b1 - a1 * b2;
        }
        __syncthreads();
        int dlt = xb * 256 + tid;
        const double* tc = Tc + dlt;
        const double* ts = Ts + dlt;
        double acc = 0.0;
#pragma unroll 8
        for (int j = 0; j < 64; ++j)
            acc += p[j] * tc[(size_t)j * S] - q[j] * ts[(size_t)j * S];
        D[(size_t)hg * S + dlt] = (float)acc;
    }
}

// ---- alpha: lane-per-row. Block = (hg, 64-row tile); 4 waves split k. ----
// Also: last 16 blocks reduce Mp (8 slabs) -> M.
__global__ __launch_bounds__(256) void k_alpha(
        const int* __restrict__ ids, const float* __restrict__ cp,
        const float* __restrict__ D, const float* __restrict__ Mp,
        float* __restrict__ M, float* __restrict__ A, int S) {
    int t = blockIdx.x;
    int tid = threadIdx.x;
    int nAlpha = (S / TS) * NQH;
    if (t >= nAlpha) {
        // Mp[8][NQH][HID] -> M[NQH][HID]
        int u = t - nAlpha;
        const float4* mp = reinterpret_cast<const float4*>(Mp);
        float4* m4 = reinterpret_cast<float4*>(M);
        const int Q = NQH * HID / 4;
        for (int j = u * 256 + tid; j < Q; j += 16 * 256) {
            float4 v[8];
#pragma unroll
            for (int sl = 0; sl < 8; ++sl) v[sl] = mp[j + sl * Q];
            float4 r;
            r.x = ((v[0].x + v[1].x) + (v[2].x + v[3].x)) +
                  ((v[4].x + v[5].x) + (v[6].x + v[7].x));
            r.y = ((v[0].y + v[1].y) + (v[2].y + v[3].y)) +
                  ((v[4].y + v[5].y) + (v[6].y + v[7].y));
            r.z = ((v[0].z + v[1].z) + (v[2].z + v[3].z)) +
                  ((v[4].z + v[5].z) + (v[6].z + v[7].z));
            r.w = ((v[0].w + v[1].w) + (v[2].w + v[3].w)) +
                  ((v[4].w + v[5].w) + (v[6].w + v[7].w));
            m4[j] = r;
        }
        return;
    }
    int tile = t >> 5;                 // 0.. S/64-1, longest rows first
    int hg = t & 31;
    int s0 = S - TS - tile * TS;
    int w = tid >> 6, lane = tid & 63;
    int sl = s0 + lane;                // this lane's row
    float csl = (float)ids[sl] * (RSQRT_HD * LOG2E);   // >= 0
    const float* Drow = D + (size_t)hg * S + sl;       // Drow[-k] = D[hg][sl-k]

    int n = s0 + TS;                   // max row length in tile
    int q4 = ((n + 15) >> 4) << 2;     // per-wave k quota, multiple of 4
    int k = w * q4;
    int k1 = (k + q4 < n) ? k + q4 : n;
    int lim = (k1 < s0 + 1) ? k1 : s0 + 1;   // fully-valid bound

    float tm = -1e30f;                 // running max of t = cp_k * D
    float mz = csl * tm;               // running max in log2-score units
    float se = 0.f, sp = 0.f;

    // fast loop: 2 chunks (8 k) per iter, all lanes valid
    for (; k + 8 <= lim; k += 8) {
        float4 cv0 = *reinterpret_cast<const float4*>(cp + k);
        float4 cv1 = *reinterpret_cast<const float4*>(cp + k + 4);
        float d0 = Drow[-k],     d1 = Drow[-(k+1)], d2 = Drow[-(k+2)], d3 = Drow[-(k+3)];
        float d4 = Drow[-(k+4)], d5 = Drow[-(k+5)], d6 = Drow[-(k+6)], d7 = Drow[-(k+7)];
        float t0 = cv0.x * d0, t1 = cv0.y * d1, t2 = cv0.z * d2, t3 = cv0.w * d3;
        float t4 = cv1.x * d4, t5 = cv1.y * d5, t6 = cv1.z * d6, t7 = cv1.w * d7;
        float m8 = fmaxf(fmaxf(fmaxf(t0, t1), fmaxf(t2, t3)),
                         fmaxf(fmaxf(t4, t5), fmaxf(t6, t7)));
        if (!__all(m8 <= tm)) {
            float ntm = fmaxf(tm, m8);
            float nmz = csl * ntm;
            float r = __builtin_amdgcn_exp2f(fminf(mz - nmz, 0.f));
            se *= r; sp *= r; tm = ntm; mz = nmz;
        }
        float e0 = __builtin_amdgcn_exp2f(fmaf(csl, t0, -mz));
        float e1 = __builtin_amdgcn_exp2f(fmaf(csl, t1, -mz));
        float e2 = __builtin_amdgcn_exp2f(fmaf(csl, t2, -mz));
        float e3 = __builtin_amdgcn_exp2f(fmaf(csl, t3, -mz));
        float e4 = __builtin_amdgcn_exp2f(fmaf(csl, t4, -mz));
        float e5 = __builtin_amdgcn_exp2f(fmaf(csl, t5, -mz));
        float e6 = __builtin_amdgcn_exp2f(fmaf(csl, t6, -mz));
        float e7 = __builtin_amdgcn_exp2f(fmaf(csl, t7, -mz));
        se += ((e0 + e1) + (e2 + e3)) + ((e4 + e5) + (e6 + e7));
        sp = fmaf(e0, cv0.x, sp); sp = fmaf(e1, cv0.y, sp);
        sp = fmaf(e2, cv0.z, sp); sp = fmaf(e3, cv0.w, sp);
        sp = fmaf(e4, cv1.x, sp); sp = fmaf(e5, cv1.y, sp);
        sp = fmaf(e6, cv1.z, sp); sp = fmaf(e7, cv1.w, sp);
    }
    for (; k + 4 <= lim; k += 4) {     // leftover full chunk
        float4 cv = *reinterpret_cast<const float4*>(cp + k);
        float d0 = Drow[-k], d1 = Drow[-(k+1)], d2 = Drow[-(k+2)], d3 = Drow[-(k+3)];
        float t0 = cv.x * d0, t1 = cv.y * d1, t2 = cv.z * d2, t3 = cv.w * d3;
        float m4 = fmaxf(fmaxf(t0, t1), fmaxf(t2, t3));
        if (!__all(m4 <= tm)) {
            float ntm = fmaxf(tm, m4);
            float nmz = csl * ntm;
            float r = __builtin_amdgcn_exp2f(fminf(mz - nmz, 0.f));
            se *= r; sp *= r; tm = ntm; mz = nmz;
        }
        float e0 = __builtin_amdgcn_exp2f(fmaf(csl, t0, -mz));
        float e1 = __builtin_amdgcn_exp2f(fmaf(csl, t1, -mz));
        float e2 = __builtin_amdgcn_exp2f(fmaf(csl, t2, -mz));
        float e3 = __builtin_amdgcn_exp2f(fmaf(csl, t3, -mz));
        se += (e0 + e1) + (e2 + e3);
        sp = fmaf(e0, cv.x, sp); sp = fmaf(e1, cv.y, sp);
        sp = fmaf(e2, cv.z, sp); sp = fmaf(e3, cv.w, sp);
    }
    // masked tail chunks (lane-dependent validity; k stays 4-aligned)
    for (; k < k1; k += 4) {
        float4 cv = *reinterpret_cast<const float4*>(cp + k);  // tiny over-read ok
        float d0 = Drow[-k], d1 = Drow[-(k+1)], d2 = Drow[-(k+2)], d3 = Drow[-(k+3)];
        bool v0 = (k + 0 <= sl) && (k + 0 < k1);
        bool v1 = (k + 1 <= sl) && (k + 1 < k1);
        bool v2 = (k + 2 <= sl) && (k + 2 < k1);
        bool v3 = (k + 3 <= sl) && (k + 3 < k1);
        float t0 = v0 ? cv.x * d0 : -1e30f;
        float t1 = v1 ? cv.y * d1 : -1e30f;
        float t2 = v2 ? cv.z * d2 : -1e30f;
        float t3 = v3 ? cv.w * d3 : -1e30f;
        float m4 = fmaxf(fmaxf(t0, t1), fmaxf(t2, t3));
        if (!__all(m4 <= tm)) {
            float ntm = fmaxf(tm, m4);
            float nmz = csl * ntm;
            float r = __builtin_amdgcn_exp2f(fminf(mz - nmz, 0.f));
            se *= r; sp *= r; tm = ntm; mz = nmz;
        }
        float e0 = __builtin_amdgcn_exp2f(fmaf(csl, t0, -mz)); e0 = v0 ? e0 : 0.f;
        float e1 = __builtin_amdgcn_exp2f(fmaf(csl, t1, -mz)); e1 = v1 ? e1 : 0.f;
        float e2 = __builtin_amdgcn_exp2f(fmaf(csl, t2, -mz)); e2 = v2 ? e2 : 0.f;
        float e3 = __builtin_amdgcn_exp2f(fmaf(csl, t3, -mz)); e3 = v3 ? e3 : 0.f;
        se += (e0 + e1) + (e2 + e3);
        sp = fmaf(e0, cv.x, sp); sp = fmaf(e1, cv.y, sp);
        sp = fmaf(e2, cv.z, sp); sp = fmaf(e3, cv.w, sp);
    }

    // 4-way merge across waves via LDS (per row)
    __shared__ float lm[4][TS], ls[4][TS], lp[4][TS];
    lm[w][lane] = mz; ls[w][lane] = se; lp[w][lane] = sp;
    __syncthreads();
    if (tid < TS) {
        float m0 = lm[0][tid], m1 = lm[1][tid], m2 = lm[2][tid], m3 = lm[3][tid];
        float mm = fmaxf(fmaxf(m0, m1), fmaxf(m2, m3));
        float r0 = __builtin_amdgcn_exp2f(fminf(m0 - mm, 0.f));
        float r1 = __builtin_amdgcn_exp2f(fminf(m1 - mm, 0.f));
        float r2 = __builtin_amdgcn_exp2f(fminf(m2 - mm, 0.f));
        float r3 = __builtin_amdgcn_exp2f(fminf(m3 - mm, 0.f));
        float seT = ls[0][tid] * r0 + ls[1][tid] * r1 + ls[2][tid] * r2 + ls[3][tid] * r3;
        float spT = lp[0][tid] * r0 + lp[1][tid] * r1 + lp[2][tid] * r2 + lp[3][tid] * r3;
        A[(size_t)hg * S + s0 + tid] = spT / seT;
    }
}

// ---- final: out[s,:] = sum_hg A[hg][s] * M[hg][:] ----
__global__ void k_out(const float* __restrict__ A, const float* __restrict__ M,
                      float* __restrict__ out, int S) {
    __shared__ float a[512];                       // [16 rows][32 hg]
    int tid = threadIdx.x;
    int s0 = blockIdx.y * 16;
    for (int v = tid; v < 512; v += 256) {
        int hg = v >> 4, r = v & 15;
        a[r * NQH + hg] = A[(size_t)hg * S + s0 + r];
    }
    __syncthreads();
    int i = blockIdx.x * 256 + tid;
    float acc[16];
#pragma unroll
    for (int rr = 0; rr < 16; ++rr) acc[rr] = 0.f;
    for (int hg = 0; hg < NQH; ++hg) {
        float mv = M[(size_t)hg * HID + i];
#pragma unroll
        for (int rr = 0; rr < 16; ++rr) acc[rr] += a[rr * NQH + hg] * mv;
    }
#pragma unroll
    for (int rr = 0; rr < 16; ++rr)
        out[(size_t)(s0 + rr) * HID + i] = acc[rr];
}

extern "C" void kernel_launch(void* const* d_in, const int* in_sizes, int n_in,
                              void* d_out, int out_size, void* d_ws, size_t ws_size,
                              hipStream_t stream) {
    const int*   ids = (const int*)d_in[0];
    const float* Wq  = (const float*)d_in[2];
    const float* Wk  = (const float*)d_in[3];
    const float* Wv  = (const float*)d_in[4];
    const float* Wo  = (const float*)d_in[5];
    float* out = (float*)d_out;
    const int S = in_sizes[0];                      // B=1, S=2048
    const int nxb = S >> 8;

    // ws layout (floats unless noted):
    //  [Pq CHQ*4096 | Pk CHQ*1024 | Pv CHQ*1024]  (Mp[8][32][4096] aliases Pq)
    //  [Sq][Sk][Sv][D 32*S][cp S][A 32*S][M 32*4096][Tc 64*S f64][Ts 64*S f64]
    // D negative over-reads land in Sq/Sk/Sv (finite); cp over-reads land in A
    // (finite, masked out).
    float* ws = (float*)d_ws;
    float* Pq = ws;
    float* Pk = Pq + (size_t)CHQ * NQH * HD;
    float* Pv = Pk + (size_t)CHQ * NKVH * HD;
    float* Mp = Pq;                                 // alias (8*32*4096 == CHQ*4096)
    float* Sq = Pv + (size_t)CHQ * NKVH * HD;
    float* Sk = Sq + HID;
    float* Sv = Sk + NKVH * HD;
    float* D  = Sv + NKVH * HD;
    float* cp = D + (size_t)NQH * S;
    float* A  = cp + S;
    float* M  = A + (size_t)NQH * S;
    double* Tc = (double*)(M + (size_t)NQH * HID);
    double* Ts = Tc + (size_t)64 * S;

    k_part<<<6 * CHQ + 64 * nxb, 256, 0, stream>>>(
        ids, Wq, Wk, Wv, Pq, Pk, Pv, cp, Tc, Ts, S);
    k_red<<<6, 256, 0, stream>>>(Pq, Pk, Pv, Sq, Sk, Sv);
    k_mid<<<1024 + NQH * nxb, 256, 0, stream>>>(Sq, Sk, Sv, Wo, Tc, Ts, Mp, D, S);
    k_alpha<<<(S / TS) * NQH + 16, 256, 0, stream>>>(ids, cp, D, Mp, M, A, S);
    k_out<<<dim3(HID / 256, S / 16), 256, 0, stream>>>(A, M, out, S);
}

// Round 8
// 85.008 us; speedup vs baseline: 1.0755x; 1.0755x over previous
//
#include <hip/hip_runtime.h>
#include <math.h>

// ---------------------------------------------------------------------------
// RopeAttentionModel reduced form:
//   x[s,:] = c_s * ones(HID)  =>  q/k/v rank-1: c_s * colsum(W)
//   scores[s,hg,k] = c_s*c_k * D[hg, s-k] / sqrt(128)
//   D[hg,d] = sum_j P[hg,j]*cos(d*f_j) - Q[hg,j]*sin(d*f_j)   (f64)
//   alpha[s,hg] = softmax-weighted mean of c_k  (scalar per (s,head))
//   out = A[S,32] @ M[32,4096],  M[hg,:] = Sv[h] . Wo[hg*128:+128, :]
// Colsums: grid-stride SEQUENTIAL streams (dense sliding window, fixed
// per-thread column). alpha: lane-per-row scan.
// ---------------------------------------------------------------------------

#define HID 4096
#define NQH 32
#define NKVH 8
#define HD 128
#define CHQ 128                   // partial depth (rows folded per column)
#define TS 64                     // s-rows per alpha block (one per lane)
#define RSQRT_HD 0.08838834764831845f
#define LOG2E    1.4426950408889634f

// sequential grid-stride column sum: thread u reads b[u + k*nth4], k=0..31.
// column (u mod cols4) is invariant since nth4 % cols4 == 0.
// Partial written flat at P[u] == P[depth][col], depth = u / cols4 in [0,128).
__device__ __forceinline__ void colsum_seq(const float* __restrict__ W,
                                           float* __restrict__ P,
                                           int nth4, int u) {
    const float4* b = reinterpret_cast<const float4*>(W);
    float ax = 0.f, ay = 0.f, az = 0.f, aw = 0.f;
#pragma unroll
    for (int k = 0; k < 32; k += 8) {
        float4 tt[8];
#pragma unroll
        for (int i = 0; i < 8; ++i) tt[i] = b[(size_t)(k + i) * nth4 + u];
#pragma unroll
        for (int i = 0; i < 8; i += 4) {
            ax += (tt[i].x + tt[i+1].x) + (tt[i+2].x + tt[i+3].x);
            ay += (tt[i].y + tt[i+1].y) + (tt[i+2].y + tt[i+3].y);
            az += (tt[i].z + tt[i+1].z) + (tt[i+2].z + tt[i+3].z);
            aw += (tt[i].w + tt[i+1].w) + (tt[i+2].w + tt[i+3].w);
        }
    }
    reinterpret_cast<float4*>(P)[u] = make_float4(ax, ay, az, aw);
}

// ---- fused: trig table + cp + Wq/Wk/Wv sequential colsums ----
__global__ __launch_bounds__(256) void k_part(
        const int* __restrict__ ids,
        const float* __restrict__ Wq, const float* __restrict__ Wk,
        const float* __restrict__ Wv,
        float* __restrict__ Pq, float* __restrict__ Pk, float* __restrict__ Pv,
        float* __restrict__ cp, double* __restrict__ Tc,
        double* __restrict__ Ts, int S) {
    int t = blockIdx.x;
    int tid = threadIdx.x;
    int nxb = S >> 8;
    int trigT = 64 * nxb;                     // 512
    if (t < trigT) {
        int j = t / nxb, xb = t - j * nxb;
        int dlt = xb * 256 + tid;
        double f = (double)(float)(1.0 / pow(10000.0, (double)j / 64.0));
        double sv, cv;
        sincos((double)dlt * f, &sv, &cv);
        Tc[(size_t)j * S + dlt] = cv;
        Ts[(size_t)j * S + dlt] = sv;
        if (j == 0) cp[dlt] = (float)ids[dlt];
    } else if (t < trigT + 512) {
        // Wq: 4096x1024 f4, 131072 threads, 32 sweeps of 128 rows
        colsum_seq(Wq, Pq, 512 * 256, (t - trigT) * 256 + tid);
    } else if (t < trigT + 640) {
        // Wk: 4096x256 f4, 32768 threads, 32 sweeps of 128 rows
        colsum_seq(Wk, Pk, 128 * 256, (t - trigT - 512) * 256 + tid);
    } else {
        colsum_seq(Wv, Pv, 128 * 256, (t - trigT - 640) * 256 + tid);
    }
}

// ---- reduce partials -> Sq, Sk, Sv (6 blocks, 16-deep batches) ----
__global__ __launch_bounds__(256) void k_red(
        const float* __restrict__ Pq, const float* __restrict__ Pk,
        const float* __restrict__ Pv, float* __restrict__ Sq,
        float* __restrict__ Sk, float* __restrict__ Sv) {
    int t = blockIdx.x;
    const float* P; float* Sd; int cols4, c4;
    if (t < 4)      { P = Pq; Sd = Sq; cols4 = NQH * HD / 4; c4 = t * 256 + threadIdx.x; }
    else if (t == 4){ P = Pk; Sd = Sk; cols4 = NKVH * HD / 4; c4 = threadIdx.x; }
    else            { P = Pv; Sd = Sv; cols4 = NKVH * HD / 4; c4 = threadIdx.x; }
    const float4* b = reinterpret_cast<const float4*>(P);
    float ax = 0.f, ay = 0.f, az = 0.f, aw = 0.f;
    for (int c = 0; c < CHQ; c += 16) {
        float4 tt[16];
#pragma unroll
        for (int i = 0; i < 16; ++i) tt[i] = b[(size_t)(c + i) * cols4 + c4];
#pragma unroll
        for (int i = 0; i < 16; i += 4) {
            ax += (tt[i].x + tt[i+1].x) + (tt[i+2].x + tt[i+3].x);
            ay += (tt[i].y + tt[i+1].y) + (tt[i+2].y + tt[i+3].y);
            az += (tt[i].z + tt[i+1].z) + (tt[i+2].z + tt[i+3].z);
            aw += (tt[i].w + tt[i+1].w) + (tt[i+2].w + tt[i+3].w);
        }
    }
    reinterpret_cast<float4*>(Sd)[c4] = make_float4(ax, ay, az, aw);
}

// ---- fused: M slabs (Sv.Wo) + D table (f64 from trig) — R6 verbatim ----
__global__ __launch_bounds__(256) void k_mid(
        const float* __restrict__ Sq, const float* __restrict__ Sk,
        const float* __restrict__ Sv, const float* __restrict__ Wo,
        const double* __restrict__ Tc, const double* __restrict__ Ts,
        float* __restrict__ Mp, float* __restrict__ D, int S) {
    int t = blockIdx.x;
    int tid = threadIdx.x;
    if (t < 512) {
        // Mp[sl][hg][:] = Sv[h, sl*32:+32] . Wo[hg*128+sl*32 : +32, :]
        int sl = t & 3, x = (t >> 2) & 3, hg = t >> 4;
        int h = hg >> 2, dbase = hg * HD + sl * 32;
        int i4 = x * 256 + tid;
        const float4* b = reinterpret_cast<const float4*>(Wo);
        const float* sv = Sv + h * HD + sl * 32;
        float ax = 0.f, ay = 0.f, az = 0.f, aw = 0.f;
#pragma unroll
        for (int bb = 0; bb < 4; ++bb) {
            size_t p = (size_t)(dbase + bb * 8) * (HID / 4) + i4;
            float4 tt[8]; float ss[8];
#pragma unroll
            for (int i = 0; i < 8; ++i) { tt[i] = b[p + (size_t)i * (HID / 4)]; ss[i] = sv[bb * 8 + i]; }
#pragma unroll
            for (int i = 0; i < 8; ++i) {
                ax += ss[i] * tt[i].x; ay += ss[i] * tt[i].y;
                az += ss[i] * tt[i].z; aw += ss[i] * tt[i].w;
            }
        }
        reinterpret_cast<float4*>(Mp)[((size_t)sl * NQH + hg) * (HID / 4) + i4] =
            make_float4(ax, ay, az, aw);
    } else {
        // D[hg, dlt] = sum_j p[j]*cos - q[j]*sin   (f64)
        __shared__ double p[64], q[64];
        int u = t - 512;
        int nxb = S >> 8;
        int hg = u / nxb, xb = u - hg * nxb, h = hg >> 2;
        if (tid < 64) {
            double a1 = Sq[hg * HD + tid], a2 = Sq[hg * HD + tid + 64];
            double b1 = Sk[h * HD + tid],  b2 = Sk[h * HD + tid + 64];
            p[tid] = a1 * b1 + a2 * b2;
            q[tid] = a2 * b1 - a1 * b2;
        }
        __syncthreads();
        int dlt = xb * 256 + tid;
        const double* tc = Tc + dlt;
        const double* ts = Ts + dlt;
        double acc = 0.0;
#pragma unroll 8
        for (int j = 0; j < 64; ++j)
            acc += p[j] * tc[(size_t)j * S] - q[j] * ts[(size_t)j * S];
        D[(size_t)hg * S + dlt] = (float)acc;
    }
}

// ---- alpha: lane-per-row. Block = (hg, 64-row tile); 4 waves split k. ----
// Also: last 16 blocks reduce Mp (4 slabs) -> M.   (R6 verbatim)
__global__ __launch_bounds__(256) void k_alpha(
        const int* __restrict__ ids, const float* __restrict__ cp,
        const float* __restrict__ D, const float* __restrict__ Mp,
        float* __restrict__ M, float* __restrict__ A, int S) {
    int t = blockIdx.x;
    int tid = threadIdx.x;
    int nAlpha = (S / TS) * NQH;
    if (t >= nAlpha) {
        // Mp[4][NQH][HID] -> M[NQH][HID]
        int u = t - nAlpha;
        const float4* mp = reinterpret_cast<const float4*>(Mp);
        float4* m4 = reinterpret_cast<float4*>(M);
        const int Q = NQH * HID / 4;
        for (int j = u * 256 + tid; j < Q; j += 16 * 256) {
            float4 a = mp[j], b = mp[j + Q], c = mp[j + 2 * Q], d = mp[j + 3 * Q];
            m4[j] = make_float4(a.x + b.x + c.x + d.x, a.y + b.y + c.y + d.y,
                                a.z + b.z + c.z + d.z, a.w + b.w + c.w + d.w);
        }
        return;
    }
    int tile = t >> 5;                 // 0.. S/64-1, longest rows first
    int hg = t & 31;
    int s0 = S - TS - tile * TS;
    int w = tid >> 6, lane = tid & 63;
    int sl = s0 + lane;                // this lane's row
    float csl = (float)ids[sl] * (RSQRT_HD * LOG2E);   // >= 0
    const float* Drow = D + (size_t)hg * S + sl;       // Drow[-k] = D[hg][sl-k]

    int n = s0 + TS;                   // max row length in tile
    int q4 = ((n + 15) >> 4) << 2;     // per-wave k quota, multiple of 4
    int k = w * q4;
    int k1 = (k + q4 < n) ? k + q4 : n;
    int lim = (k1 < s0 + 1) ? k1 : s0 + 1;   // fully-valid bound

    float tm = -1e30f;                 // running max of t = cp_k * D
    float mz = csl * tm;               // running max in log2-score units
    float se = 0.f, sp = 0.f;

    // fast loop: 2 chunks (8 k) per iter, all lanes valid
    for (; k + 8 <= lim; k += 8) {
        float4 cv0 = *reinterpret_cast<const float4*>(cp + k);
        float4 cv1 = *reinterpret_cast<const float4*>(cp + k + 4);
        float d0 = Drow[-k],     d1 = Drow[-(k+1)], d2 = Drow[-(k+2)], d3 = Drow[-(k+3)];
        float d4 = Drow[-(k+4)], d5 = Drow[-(k+5)], d6 = Drow[-(k+6)], d7 = Drow[-(k+7)];
        float t0 = cv0.x * d0, t1 = cv0.y * d1, t2 = cv0.z * d2, t3 = cv0.w * d3;
        float t4 = cv1.x * d4, t5 = cv1.y * d5, t6 = cv1.z * d6, t7 = cv1.w * d7;
        float m8 = fmaxf(fmaxf(fmaxf(t0, t1), fmaxf(t2, t3)),
                         fmaxf(fmaxf(t4, t5), fmaxf(t6, t7)));
        if (!__all(m8 <= tm)) {
            float ntm = fmaxf(tm, m8);
            float nmz = csl * ntm;
            float r = __builtin_amdgcn_exp2f(fminf(mz - nmz, 0.f));
            se *= r; sp *= r; tm = ntm; mz = nmz;
        }
        float e0 = __builtin_amdgcn_exp2f(fmaf(csl, t0, -mz));
        float e1 = __builtin_amdgcn_exp2f(fmaf(csl, t1, -mz));
        float e2 = __builtin_amdgcn_exp2f(fmaf(csl, t2, -mz));
        float e3 = __builtin_amdgcn_exp2f(fmaf(csl, t3, -mz));
        float e4 = __builtin_amdgcn_exp2f(fmaf(csl, t4, -mz));
        float e5 = __builtin_amdgcn_exp2f(fmaf(csl, t5, -mz));
        float e6 = __builtin_amdgcn_exp2f(fmaf(csl, t6, -mz));
        float e7 = __builtin_amdgcn_exp2f(fmaf(csl, t7, -mz));
        se += ((e0 + e1) + (e2 + e3)) + ((e4 + e5) + (e6 + e7));
        sp = fmaf(e0, cv0.x, sp); sp = fmaf(e1, cv0.y, sp);
        sp = fmaf(e2, cv0.z, sp); sp = fmaf(e3, cv0.w, sp);
        sp = fmaf(e4, cv1.x, sp); sp = fmaf(e5, cv1.y, sp);
        sp = fmaf(e6, cv1.z, sp); sp = fmaf(e7, cv1.w, sp);
    }
    for (; k + 4 <= lim; k += 4) {     // leftover full chunk
        float4 cv = *reinterpret_cast<const float4*>(cp + k);
        float d0 = Drow[-k], d1 = Drow[-(k+1)], d2 = Drow[-(k+2)], d3 = Drow[-(k+3)];
        float t0 = cv.x * d0, t1 = cv.y * d1, t2 = cv.z * d2, t3 = cv.w * d3;
        float m4 = fmaxf(fmaxf(t0, t1), fmaxf(t2, t3));
        if (!__all(m4 <= tm)) {
            float ntm = fmaxf(tm, m4);
            float nmz = csl * ntm;
            float r = __builtin_amdgcn_exp2f(fminf(mz - nmz, 0.f));
            se *= r; sp *= r; tm = ntm; mz = nmz;
        }
        float e0 = __builtin_amdgcn_exp2f(fmaf(csl, t0, -mz));
        float e1 = __builtin_amdgcn_exp2f(fmaf(csl, t1, -mz));
        float e2 = __builtin_amdgcn_exp2f(fmaf(csl, t2, -mz));
        float e3 = __builtin_amdgcn_exp2f(fmaf(csl, t3, -mz));
        se += (e0 + e1) + (e2 + e3);
        sp = fmaf(e0, cv.x, sp); sp = fmaf(e1, cv.y, sp);
        sp = fmaf(e2, cv.z, sp); sp = fmaf(e3, cv.w, sp);
    }
    // masked tail chunks (lane-dependent validity; k stays 4-aligned)
    for (; k < k1; k += 4) {
        float4 cv = *reinterpret_cast<const float4*>(cp + k);  // tiny over-read ok
        float d0 = Drow[-k], d1 = Drow[-(k+1)], d2 = Drow[-(k+2)], d3 = Drow[-(k+3)];
        bool v0 = (k + 0 <= sl) && (k + 0 < k1);
        bool v1 = (k + 1 <= sl) && (k + 1 < k1);
        bool v2 = (k + 2 <= sl) && (k + 2 < k1);
        bool v3 = (k + 3 <= sl) && (k + 3 < k1);
        float t0 = v0 ? cv.x * d0 : -1e30f;
        float t1 = v1 ? cv.y * d1 : -1e30f;
        float t2 = v2 ? cv.z * d2 : -1e30f;
        float t3 = v3 ? cv.w * d3 : -1e30f;
        float m4 = fmaxf(fmaxf(t0, t1), fmaxf(t2, t3));
        if (!__all(m4 <= tm)) {
            float ntm = fmaxf(tm, m4);
            float nmz = csl * ntm;
            float r = __builtin_amdgcn_exp2f(fminf(mz - nmz, 0.f));
            se *= r; sp *= r; tm = ntm; mz = nmz;
        }
        float e0 = __builtin_amdgcn_exp2f(fmaf(csl, t0, -mz)); e0 = v0 ? e0 : 0.f;
        float e1 = __builtin_amdgcn_exp2f(fmaf(csl, t1, -mz)); e1 = v1 ? e1 : 0.f;
        float e2 = __builtin_amdgcn_exp2f(fmaf(csl, t2, -mz)); e2 = v2 ? e2 : 0.f;
        float e3 = __builtin_amdgcn_exp2f(fmaf(csl, t3, -mz)); e3 = v3 ? e3 : 0.f;
        se += (e0 + e1) + (e2 + e3);
        sp = fmaf(e0, cv.x, sp); sp = fmaf(e1, cv.y, sp);
        sp = fmaf(e2, cv.z, sp); sp = fmaf(e3, cv.w, sp);
    }

    // 4-way merge across waves via LDS (per row)
    __shared__ float lm[4][TS], ls[4][TS], lp[4][TS];
    lm[w][lane] = mz; ls[w][lane] = se; lp[w][lane] = sp;
    __syncthreads();
    if (tid < TS) {
        float m0 = lm[0][tid], m1 = lm[1][tid], m2 = lm[2][tid], m3 = lm[3][tid];
        float mm = fmaxf(fmaxf(m0, m1), fmaxf(m2, m3));
        float r0 = __builtin_amdgcn_exp2f(fminf(m0 - mm, 0.f));
        float r1 = __builtin_amdgcn_exp2f(fminf(m1 - mm, 0.f));
        float r2 = __builtin_amdgcn_exp2f(fminf(m2 - mm, 0.f));
        float r3 = __builtin_amdgcn_exp2f(fminf(m3 - mm, 0.f));
        float seT = ls[0][tid] * r0 + ls[1][tid] * r1 + ls[2][tid] * r2 + ls[3][tid] * r3;
        float spT = lp[0][tid] * r0 + lp[1][tid] * r1 + lp[2][tid] * r2 + lp[3][tid] * r3;
        A[(size_t)hg * S + s0 + tid] = spT / seT;
    }
}

// ---- final: out[s,:] = sum_hg A[hg][s] * M[hg][:] ----
__global__ void k_out(const float* __restrict__ A, const float* __restrict__ M,
                      float* __restrict__ out, int S) {
    __shared__ float a[512];                       // [16 rows][32 hg]
    int tid = threadIdx.x;
    int s0 = blockIdx.y * 16;
    for (int v = tid; v < 512; v += 256) {
        int hg = v >> 4, r = v & 15;
        a[r * NQH + hg] = A[(size_t)hg * S + s0 + r];
    }
    __syncthreads();
    int i = blockIdx.x * 256 + tid;
    float acc[16];
#pragma unroll
    for (int rr = 0; rr < 16; ++rr) acc[rr] = 0.f;
    for (int hg = 0; hg < NQH; ++hg) {
        float mv = M[(size_t)hg * HID + i];
#pragma unroll
        for (int rr = 0; rr < 16; ++rr) acc[rr] += a[rr * NQH + hg] * mv;
    }
#pragma unroll
    for (int rr = 0; rr < 16; ++rr)
        out[(size_t)(s0 + rr) * HID + i] = acc[rr];
}

extern "C" void kernel_launch(void* const* d_in, const int* in_sizes, int n_in,
                              void* d_out, int out_size, void* d_ws, size_t ws_size,
                              hipStream_t stream) {
    const int*   ids = (const int*)d_in[0];
    const float* Wq  = (const float*)d_in[2];
    const float* Wk  = (const float*)d_in[3];
    const float* Wv  = (const float*)d_in[4];
    const float* Wo  = (const float*)d_in[5];
    float* out = (float*)d_out;
    const int S = in_sizes[0];                      // B=1, S=2048
    const int nxb = S >> 8;

    // ws layout (floats unless noted):
    //  [Pq 128*4096 | Pk 128*1024 | Pv 128*1024]  (Mp[4][32][4096] aliases Pq)
    //  [Sq][Sk][Sv][D 32*S][cp S][A 32*S][M 32*4096][Tc 64*S f64][Ts 64*S f64]
    // D negative over-reads land in Sq/Sk/Sv (finite); cp over-reads land in A
    // (finite, masked out).
    float* ws = (float*)d_ws;
    float* Pq = ws;
    float* Pk = Pq + (size_t)CHQ * NQH * HD;
    float* Pv = Pk + (size_t)CHQ * NKVH * HD;
    float* Mp = Pq;                                 // alias (4*32*4096 == CHQ*4096)
    float* Sq = Pv + (size_t)CHQ * NKVH * HD;
    float* Sk = Sq + HID;
    float* Sv = Sk + NKVH * HD;
    float* D  = Sv + NKVH * HD;
    float* cp = D + (size_t)NQH * S;
    float* A  = cp + S;
    float* M  = A + (size_t)NQH * S;
    double* Tc = (double*)(M + (size_t)NQH * HID);
    double* Ts = Tc + (size_t)64 * S;

    k_part<<<64 * nxb + 512 + 128 + 128, 256, 0, stream>>>(
        ids, Wq, Wk, Wv, Pq, Pk, Pv, cp, Tc, Ts, S);
    k_red<<<6, 256, 0, stream>>>(Pq, Pk, Pv, Sq, Sk, Sv);
    k_mid<<<512 + NQH * nxb, 256, 0, stream>>>(Sq, Sk, Sv, Wo, Tc, Ts, Mp, D, S);
    k_alpha<<<(S / TS) * NQH + 16, 256, 0, stream>>>(ids, cp, D, Mp, M, A, S);
    k_out<<<dim3(HID / 256, S / 16), 256, 0, stream>>>(A, M, out, S);
}